// Round 11
// baseline (456.125 us; speedup 1.0000x reference)
//
#include <hip/hip_runtime.h>

#define D 64
#define BK_SHIFT 6              // 64 nodes per bucket
#define BK_CAP 8192             // staged entries per bucket (mean ~1600)
#define NBLK 256                // radix pass blocks
#define PAD_SLACK 2048          // per-bucket col padding slack (64 nodes * <=32)

__device__ __forceinline__ float bfbits2f(unsigned short b) {
    union { unsigned int u; float f; } c;
    c.u = ((unsigned int)b) << 16;
    return c.f;
}

__device__ __forceinline__ unsigned short f2bfbits(float f) {
    union { float f; unsigned int u; } c;
    c.f = f;
    unsigned int u = c.u;
    unsigned int lsb = (u >> 16) & 1u;
    u += 0x7fffu + lsb;           // round-to-nearest-even
    return (unsigned short)(u >> 16);
}

__device__ __forceinline__ float ldmix(const void* p, size_t i, int isf32) {
    return isf32 ? ((const float*)p)[i] : bfbits2f(((const unsigned short*)p)[i]);
}

// ---- param conversion + dtype sniff + zero rows + counter init -------------
#define OW1 0
#define OW2 4096
#define OW3 8192
#define OB1 12288
#define OB2 12352
#define OB3 12416
#define OG  12480
#define OBE 12544
#define OPA 12608

__global__ void setup_kernel(const void* W1, const void* b1, const void* W2, const void* b2,
                             const void* W3, const void* b3, const void* pa, const void* g,
                             const void* be, int* __restrict__ flag, int* __restrict__ done,
                             float* __restrict__ P,
                             unsigned short* __restrict__ Xs, unsigned short* __restrict__ Xs2,
                             int N) {
    __shared__ int sflag;
    int t = threadIdx.x;                 // one block of 256
    if (t == 0) sflag = 0;
    __syncthreads();
    // sniff: read first 256 ushorts of W1 as bf16; fp32 data decodes to junk
    {
        float v = bfbits2f(((const unsigned short*)W1)[t]);
        if (!(v == v) || fabsf(v) > 1e4f) atomicOr(&sflag, 1);
    }
    __syncthreads();
    int isf = sflag;
    if (t == 0) { *flag = isf; *done = 0; }
    for (int i = t; i < D * D; i += 256) {
        P[OW1 + i] = ldmix(W1, i, isf);
        P[OW2 + i] = ldmix(W2, i, isf);
        P[OW3 + i] = ldmix(W3, i, isf);
    }
    if (t < D) {
        P[OB1 + t] = ldmix(b1, t, isf);
        P[OB2 + t] = ldmix(b2, t, isf);
        P[OB3 + t] = ldmix(b3, t, isf);
        P[OG  + t] = ldmix(g,  t, isf);
        P[OBE + t] = ldmix(be, t, isf);
        // zero row (index N) for pad edges, both ping-pong tables
        Xs [(size_t)N * D + t] = 0;
        Xs2[(size_t)N * D + t] = 0;
    }
    if (t == 0) P[OPA] = ldmix(pa, 0, isf);
}

// ---- deterministic two-pass radix binning (no global atomics) --------------
// H layout: H[bucket * NBLK + block]

__global__ void binA1_kernel(const int* __restrict__ dst, int E, int NB, int CH,
                             int* __restrict__ H) {
    __shared__ int h[1024];
    int t = threadIdx.x, bb = blockIdx.x;
    for (int i = t; i < NB; i += 256) h[i] = 0;
    __syncthreads();
    int beg = bb * CH, end = beg + CH; if (end > E) end = E;
    for (int e = beg + t; e < end; e += 256)
        atomicAdd(&h[dst[e] >> BK_SHIFT], 1);
    __syncthreads();
    for (int i = t; i < NB; i += 256) H[i * NBLK + bb] = h[i];
}

// per-bucket scan of block-counts; last block also scans totals -> bucket_beg
__global__ void binA2_kernel(int* __restrict__ H, int* __restrict__ T,
                             int* __restrict__ bucket_beg, int* __restrict__ done, int NB) {
    __shared__ int ws[4];
    __shared__ int wx[4];
    int b = blockIdx.x, t = threadIdx.x;
    int lane = t & 63, wid = t >> 6;
    int v = H[b * NBLK + t];
    int incl = v;
#pragma unroll
    for (int off = 1; off < 64; off <<= 1) {
        int u = __shfl_up(incl, off, 64);
        if (lane >= off) incl += u;
    }
    if (lane == 63) ws[wid] = incl;
    __syncthreads();
    if (t == 0) {
        int s = 0;
#pragma unroll
        for (int j = 0; j < 4; ++j) { wx[j] = s; s += ws[j]; }
        atomicExch(&T[b], s);            // device-coherent publish
    }
    __syncthreads();
    H[b * NBLK + t] = wx[wid] + incl - v;
    // ---- last finishing block scans T[0..NB-1] -> bucket_beg ----
    __threadfence();
    __shared__ int amLast;
    if (t == 0) amLast = (atomicAdd(done, 1) == gridDim.x - 1) ? 1 : 0;
    __syncthreads();
    if (!amLast) return;
    int base = t * 4;
    int v0 = (base + 0 < NB) ? atomicAdd(&T[base + 0], 0) : 0;
    int v1 = (base + 1 < NB) ? atomicAdd(&T[base + 1], 0) : 0;
    int v2 = (base + 2 < NB) ? atomicAdd(&T[base + 2], 0) : 0;
    int v3 = (base + 3 < NB) ? atomicAdd(&T[base + 3], 0) : 0;
    int s4 = v0 + v1 + v2 + v3;
    int incl2 = s4;
#pragma unroll
    for (int off = 1; off < 64; off <<= 1) {
        int u = __shfl_up(incl2, off, 64);
        if (lane >= off) incl2 += u;
    }
    __shared__ int ws2[4];
    if (lane == 63) ws2[wid] = incl2;
    __syncthreads();
    int add = 0;
    for (int j = 0; j < wid; ++j) add += ws2[j];
    int e = add + incl2 - s4;
    if (base + 0 < NB) { bucket_beg[base + 0] = e; e += v0; }
    if (base + 1 < NB) { bucket_beg[base + 1] = e; e += v1; }
    if (base + 2 < NB) { bucket_beg[base + 2] = e; e += v2; }
    if (base + 3 < NB) { bucket_beg[base + 3] = e; e += v3; }
    if (base < NB && NB <= base + 4) bucket_beg[NB] = e;
}

// scatter edges into bucket-grouped tmp via LDS cursors (deterministic ranges)
__global__ void binA4_kernel(const int* __restrict__ src, const int* __restrict__ dst,
                             const int* __restrict__ H, const int* __restrict__ bucket_beg,
                             unsigned int* __restrict__ tmp, int E, int NB, int CH) {
    __shared__ int O[1024];
    int t = threadIdx.x, bb = blockIdx.x;
    for (int i = t; i < NB; i += 256) O[i] = bucket_beg[i] + H[i * NBLK + bb];
    __syncthreads();
    int beg = bb * CH, end = beg + CH; if (end > E) end = E;
    for (int e = beg + t; e < end; e += 256) {
        int d = dst[e];
        int p = atomicAdd(&O[d >> BK_SHIFT], 1);
        tmp[p] = ((unsigned int)src[e] << BK_SHIFT) | (unsigned int)(d & 63);
    }
}

// one block per bucket: per-node count + padded scan (>=32) + L2-local scatter +
// pad-fill with zero-row index N + fused layer-1 prescale
__global__ void binB_kernel(const unsigned int* __restrict__ tmp, const int* __restrict__ bucket_beg,
                            int* __restrict__ row_beg, int* __restrict__ cnt,
                            float* __restrict__ dinv, int* __restrict__ col,
                            const void* __restrict__ X, const int* __restrict__ flag,
                            unsigned short* __restrict__ Xs, int N) {
    __shared__ unsigned int ent[BK_CAP];
    __shared__ int lv[64], lpv[64], lpe[64], lcur[64];
    __shared__ float ldv[64];
    int b = blockIdx.x, t = threadIdx.x;
    int beg = bucket_beg[b], end = bucket_beg[b + 1];
    int colbase = beg + b * PAD_SLACK;
    int m = end - beg;
    bool staged = (m <= BK_CAP);
    if (t < 64) lv[t] = 0;
    __syncthreads();
    for (int i = t; i < m; i += 256) {
        unsigned int e = tmp[beg + i];
        if (staged) ent[i] = e;
        atomicAdd(&lv[e & 63u], 1);
    }
    __syncthreads();
    if (t < 64) {
        int v  = lv[t];
        int pv = (v + 31) & ~31;             // padded to multiple of 32, minimum 32
        if (pv == 0) pv = 32;
        int incl = pv;
#pragma unroll
        for (int off = 1; off < 64; off <<= 1) {
            int u = __shfl_up(incl, off, 64);
            if (t >= off) incl += u;
        }
        int pexcl = incl - pv;
        lpv[t]  = pv;
        lpe[t]  = pexcl;
        lcur[t] = pexcl;
        float dv = rsqrtf((float)(v + 1));
        ldv[t] = dv;
        int node = b * 64 + t;
        if (node < N) {
            row_beg[node] = colbase + pexcl;
            cnt[node]     = pv;              // padded count (loop bound)
            dinv[node]    = dv;
        }
    }
    __syncthreads();
    for (int i = t; i < m; i += 256) {
        unsigned int e = staged ? ent[i] : tmp[beg + i];
        int p = atomicAdd(&lcur[e & 63u], 1);
        col[colbase + p] = (int)(e >> BK_SHIFT);
    }
    // pad fill: positions [v, pv) of each node get the zero-row index N
    for (int i = t; i < 64 * 32; i += 256) {
        int nl = i >> 5, j = i & 31;
        int idx = lv[nl] + j;
        if (idx < lpv[nl]) col[colbase + lpe[nl] + idx] = N;
    }
    // fused layer-1 prescale: Xs[node][f] = bf16(dinv * X[node][f])
    int isf = *flag;
    for (int i = t; i < 64 * 64; i += 256) {
        int nl = i >> 6, f = i & 63;
        int node = b * 64 + nl;
        if (node < N)
            Xs[(size_t)node * D + f] = f2bfbits(ldv[nl] * ldmix(X, (size_t)node * D + f, isf));
    }
}

// ---- feature kernels -------------------------------------------------------

__device__ __forceinline__ void acc8(float* a, uint4 v) {
    a[0] += bfbits2f((unsigned short)(v.x & 0xffffu));
    a[1] += bfbits2f((unsigned short)(v.x >> 16));
    a[2] += bfbits2f((unsigned short)(v.y & 0xffffu));
    a[3] += bfbits2f((unsigned short)(v.y >> 16));
    a[4] += bfbits2f((unsigned short)(v.z & 0xffffu));
    a[5] += bfbits2f((unsigned short)(v.z >> 16));
    a[6] += bfbits2f((unsigned short)(v.w & 0xffffu));
    a[7] += bfbits2f((unsigned short)(v.w >> 16));
}

// quad static-trip gather: one wave aggregates FOUR nodes; first 32-edge chunk
// of all four nodes issued as 16 back-to-back row loads. pcnt >= 32 guaranteed.
__device__ __forceinline__ void agg_quad(const unsigned short* __restrict__ Xs,
                                         const int* __restrict__ bg, const int* __restrict__ pc,
                                         const int* __restrict__ col,
                                         const float* __restrict__ dn, const int* __restrict__ nd,
                                         int lane, float x[4][8]) {
    const int slot = lane >> 3;
    const int sub  = lane & 7;
    uint4 sv[4];
#pragma unroll
    for (int m = 0; m < 4; ++m)
        sv[m] = *((const uint4*)(Xs + ((size_t)nd[m] << 6)) + sub);
    float a[4][8];
#pragma unroll
    for (int m = 0; m < 4; ++m)
#pragma unroll
        for (int j = 0; j < 8; ++j) a[m][j] = 0.f;
    // edge indices for first chunk of all 4 nodes (issue all col reads first)
    int s[4][4];
#pragma unroll
    for (int m = 0; m < 4; ++m) {
        const int* cb = col + bg[m];
        s[m][0] = cb[slot];
        s[m][1] = cb[8  + slot];
        s[m][2] = cb[16 + slot];
        s[m][3] = cb[24 + slot];
    }
    // 16 row loads back-to-back, then consume
    uint4 v[4][4];
#pragma unroll
    for (int m = 0; m < 4; ++m)
#pragma unroll
        for (int i = 0; i < 4; ++i)
            v[m][i] = *((const uint4*)(Xs + ((size_t)s[m][i] << 6)) + sub);
#pragma unroll
    for (int m = 0; m < 4; ++m)
#pragma unroll
        for (int i = 0; i < 4; ++i) acc8(a[m], v[m][i]);
    // rare tails (deg > 32)
#pragma unroll
    for (int m = 0; m < 4; ++m) {
        for (int c = 32; c < pc[m]; c += 32) {
            const int* cb = col + bg[m] + c;
            int t0 = cb[slot], t1 = cb[8 + slot], t2 = cb[16 + slot], t3 = cb[24 + slot];
            uint4 w0 = *((const uint4*)(Xs + ((size_t)t0 << 6)) + sub);
            uint4 w1 = *((const uint4*)(Xs + ((size_t)t1 << 6)) + sub);
            uint4 w2 = *((const uint4*)(Xs + ((size_t)t2 << 6)) + sub);
            uint4 w3 = *((const uint4*)(Xs + ((size_t)t3 << 6)) + sub);
            acc8(a[m], w0); acc8(a[m], w1); acc8(a[m], w2); acc8(a[m], w3);
        }
    }
    // reduce the 8 row-slots for all nodes (flip lane bits 3..5)
#pragma unroll
    for (int off = 8; off < 64; off <<= 1)
#pragma unroll
        for (int m = 0; m < 4; ++m)
#pragma unroll
            for (int j = 0; j < 8; ++j) a[m][j] += __shfl_xor(a[m][j], off, 64);
#pragma unroll
    for (int m = 0; m < 4; ++m) {
        acc8(a[m], sv[m]);
#pragma unroll
        for (int j = 0; j < 8; ++j) x[m][j] = dn[m] * a[m][j];
    }
}

// quad wave GEMM: each Wl value read once, used for 4 nodes
__device__ __forceinline__ void wave_gemm_quad(const float* __restrict__ Wl,
                                               float x[4][8], int lane, float* o) {
    float a0[4] = {0.f, 0.f, 0.f, 0.f}, a1[4] = {0.f, 0.f, 0.f, 0.f};
#pragma unroll
    for (int k = 0; k < D; k += 2) {
        float w0 = Wl[(k    ) * D + lane];
        float w1 = Wl[(k + 1) * D + lane];
#pragma unroll
        for (int m = 0; m < 4; ++m) {
            a0[m] = fmaf(__shfl(x[m][(k    ) & 7], (k    ) >> 3, 64), w0, a0[m]);
            a1[m] = fmaf(__shfl(x[m][(k + 1) & 7], (k + 1) >> 3, 64), w1, a1[m]);
        }
    }
#pragma unroll
    for (int m = 0; m < 4; ++m) o[m] = a0[m] + a1[m];
}

__global__ void __launch_bounds__(256)
agg_gemm_kernel(const unsigned short* __restrict__ Xs,
                const int* __restrict__ row_beg, const int* __restrict__ cnt,
                const int* __restrict__ col, const float* __restrict__ dinv,
                const float* __restrict__ W, const float* __restrict__ b,
                const float* __restrict__ pa,
                unsigned short* __restrict__ Xout, int n) {
    __shared__ float Wl[D * D];
    int t = threadIdx.x;
    for (int i = t; i < D * D; i += 256) Wl[i] = W[i];
    __syncthreads();
    int wid = t >> 6, lane = t & 63;
    int n0 = blockIdx.x * 16 + wid * 4;
    if (n0 >= n) return;
    int nd[4], bg[4], pc[4];
    float dn[4];
#pragma unroll
    for (int m = 0; m < 4; ++m) {
        int nm = n0 + m;
        bool ok = (nm < n);
        nd[m] = ok ? nm : n;
        bg[m] = ok ? row_beg[nm] : 0;
        pc[m] = ok ? cnt[nm] : 32;
        dn[m] = ok ? dinv[nm] : 0.f;
    }
    float bl = b[lane];
    float pr = pa[0];
    float x[4][8];
    agg_quad(Xs, bg, pc, col, dn, nd, lane, x);
    float o[4];
    wave_gemm_quad(Wl, x, lane, o);
#pragma unroll
    for (int m = 0; m < 4; ++m) {
        float acc = o[m] + bl;
        acc = (acc >= 0.f) ? acc : pr * acc;
        acc *= dn[m];                         // prescale for next layer
        if (n0 + m < n) Xout[(size_t)(n0 + m) * D + lane] = f2bfbits(acc);
    }
}

__global__ void __launch_bounds__(256)
agg_gemm_ln_kernel(const unsigned short* __restrict__ Xs,
                   const int* __restrict__ row_beg, const int* __restrict__ cnt,
                   const int* __restrict__ col, const float* __restrict__ dinv,
                   const float* __restrict__ W, const float* __restrict__ b,
                   const float* __restrict__ g, const float* __restrict__ be,
                   const int* __restrict__ flag, void* __restrict__ out, int n) {
    __shared__ float Wl[D * D];
    int t = threadIdx.x;
    for (int i = t; i < D * D; i += 256) Wl[i] = W[i];
    __syncthreads();
    int wid = t >> 6, lane = t & 63;
    int n0 = blockIdx.x * 16 + wid * 4;
    if (n0 >= n) return;
    int nd[4], bg[4], pc[4];
    float dn[4];
#pragma unroll
    for (int m = 0; m < 4; ++m) {
        int nm = n0 + m;
        bool ok = (nm < n);
        nd[m] = ok ? nm : n;
        bg[m] = ok ? row_beg[nm] : 0;
        pc[m] = ok ? cnt[nm] : 32;
        dn[m] = ok ? dinv[nm] : 0.f;
    }
    int   isf = *flag;
    float bl  = b[lane];
    float gl  = g[lane];
    float bel = be[lane];
    float x[4][8];
    agg_quad(Xs, bg, pc, col, dn, nd, lane, x);
    float o[4];
    wave_gemm_quad(Wl, x, lane, o);
    float acc[4], s[4];
#pragma unroll
    for (int m = 0; m < 4; ++m) { acc[m] = o[m] + bl; s[m] = acc[m]; }
#pragma unroll
    for (int off = 32; off > 0; off >>= 1)
#pragma unroll
        for (int m = 0; m < 4; ++m) s[m] += __shfl_xor(s[m], off, 64);
    float dfe[4], vv[4];
#pragma unroll
    for (int m = 0; m < 4; ++m) { dfe[m] = acc[m] - s[m] * (1.f / 64.f); vv[m] = dfe[m] * dfe[m]; }
#pragma unroll
    for (int off = 32; off > 0; off >>= 1)
#pragma unroll
        for (int m = 0; m < 4; ++m) vv[m] += __shfl_xor(vv[m], off, 64);
#pragma unroll
    for (int m = 0; m < 4; ++m) {
        float r = rsqrtf(vv[m] * (1.f / 64.f) + 1e-5f);
        float ov = dfe[m] * r * gl + bel;
        if (n0 + m < n) {
            size_t oi = (size_t)(n0 + m) * D + lane;
            if (isf) ((float*)out)[oi] = ov;
            else     ((unsigned short*)out)[oi] = f2bfbits(ov);
        }
    }
}

// ---- driver ----------------------------------------------------------------

extern "C" void kernel_launch(void* const* d_in, const int* in_sizes, int n_in,
                              void* d_out, int out_size, void* d_ws, size_t ws_size,
                              hipStream_t stream) {
    const void* X   = d_in[0];
    const void* W1  = d_in[1];
    const void* b1  = d_in[2];
    const void* W2  = d_in[3];
    const void* b2  = d_in[4];
    const void* W3  = d_in[5];
    const void* b3  = d_in[6];
    const void* pa  = d_in[7];
    const void* g   = d_in[8];
    const void* be  = d_in[9];
    const int*  ei  = (const int*)d_in[10];

    int N = in_sizes[0] / D;
    int E = in_sizes[10] / 2;
    int NB = (N + 63) >> BK_SHIFT;   // <= 1024 for N <= 65536
    int CH = (E + NBLK - 1) / NBLK;  // edges per radix block
    const int* src = ei;
    const int* dst = ei + E;

    char* p = (char*)d_ws;
    auto alloc = [&](size_t bytes) { void* q = (void*)p; p += (bytes + 255) & ~(size_t)255; return q; };
    int*            flag       = (int*)alloc(4);
    int*            done       = (int*)alloc(4);
    int*            H          = (int*)alloc((size_t)1024 * NBLK * 4);
    int*            T          = (int*)alloc(1024 * 4);
    int*            bucket_beg = (int*)alloc(1025 * 4);
    int*            row_beg    = (int*)alloc((size_t)N * 4);
    int*            cnt        = (int*)alloc((size_t)N * 4);
    float*          dinv       = (float*)alloc((size_t)N * 4);
    int*            col        = (int*)alloc(((size_t)E + (size_t)NB * PAD_SLACK) * 4);
    unsigned int*   tmp        = (unsigned int*)alloc((size_t)E * 4);
    float*          P          = (float*)alloc((size_t)(OPA + 1) * 4);
    unsigned short* Xs         = (unsigned short*)alloc((size_t)(N + 1) * D * 2);
    unsigned short* Xs2        = (unsigned short*)alloc((size_t)(N + 1) * D * 2);
    (void)ws_size; (void)n_in; (void)out_size;

    setup_kernel<<<1, 256, 0, stream>>>(W1, b1, W2, b2, W3, b3, pa, g, be,
                                        flag, done, P, Xs, Xs2, N);

    binA1_kernel<<<NBLK, 256, 0, stream>>>(dst, E, NB, CH, H);
    binA2_kernel<<<NB, 256, 0, stream>>>(H, T, bucket_beg, done, NB);
    binA4_kernel<<<NBLK, 256, 0, stream>>>(src, dst, H, bucket_beg, tmp, E, NB, CH);
    binB_kernel<<<NB, 256, 0, stream>>>(tmp, bucket_beg, row_beg, cnt, dinv, col, X, flag, Xs, N);

    int ngb = (N + 15) / 16;         // 16 nodes per 256-thread block (4 per wave)

    agg_gemm_kernel   <<<ngb, 256, 0, stream>>>(Xs,  row_beg, cnt, col, dinv, P + OW1, P + OB1, P + OPA, Xs2, N);
    agg_gemm_kernel   <<<ngb, 256, 0, stream>>>(Xs2, row_beg, cnt, col, dinv, P + OW2, P + OB2, P + OPA, Xs,  N);
    agg_gemm_ln_kernel<<<ngb, 256, 0, stream>>>(Xs,  row_beg, cnt, col, dinv, P + OW3, P + OB3, P + OG, P + OBE, flag, d_out, N);
}

// Round 13
// 387.878 us; speedup vs baseline: 1.1760x; 1.1760x over previous
//
#include <hip/hip_runtime.h>

#define D 64
#define BK_SHIFT 6              // 64 nodes per bucket
#define BK_CAP 8192             // staged entries per bucket (mean ~1600)
#define NBLK 256                // radix pass blocks
#define PAD_SLACK 2048          // per-bucket col padding slack (64 nodes * <=32)

typedef unsigned int v4u __attribute__((ext_vector_type(4)));   // native vector for nt loads

__device__ __forceinline__ float bfbits2f(unsigned short b) {
    union { unsigned int u; float f; } c;
    c.u = ((unsigned int)b) << 16;
    return c.f;
}

__device__ __forceinline__ unsigned short f2bfbits(float f) {
    union { float f; unsigned int u; } c;
    c.f = f;
    unsigned int u = c.u;
    unsigned int lsb = (u >> 16) & 1u;
    u += 0x7fffu + lsb;           // round-to-nearest-even
    return (unsigned short)(u >> 16);
}

__device__ __forceinline__ float ldmix(const void* p, size_t i, int isf32) {
    return isf32 ? ((const float*)p)[i] : bfbits2f(((const unsigned short*)p)[i]);
}

// ---- param conversion + dtype sniff + zero rows + counter init -------------
#define OW1 0
#define OW2 4096
#define OW3 8192
#define OB1 12288
#define OB2 12352
#define OB3 12416
#define OG  12480
#define OBE 12544
#define OPA 12608

__global__ void setup_kernel(const void* W1, const void* b1, const void* W2, const void* b2,
                             const void* W3, const void* b3, const void* pa, const void* g,
                             const void* be, int* __restrict__ flag, int* __restrict__ done,
                             float* __restrict__ P,
                             unsigned short* __restrict__ Xs, unsigned short* __restrict__ Xs2,
                             int N) {
    __shared__ int sflag;
    int t = threadIdx.x;                 // one block of 256
    if (t == 0) sflag = 0;
    __syncthreads();
    {
        float v = bfbits2f(((const unsigned short*)W1)[t]);
        if (!(v == v) || fabsf(v) > 1e4f) atomicOr(&sflag, 1);
    }
    __syncthreads();
    int isf = sflag;
    if (t == 0) { *flag = isf; *done = 0; }
    for (int i = t; i < D * D; i += 256) {
        P[OW1 + i] = ldmix(W1, i, isf);
        P[OW2 + i] = ldmix(W2, i, isf);
        P[OW3 + i] = ldmix(W3, i, isf);
    }
    if (t < D) {
        P[OB1 + t] = ldmix(b1, t, isf);
        P[OB2 + t] = ldmix(b2, t, isf);
        P[OB3 + t] = ldmix(b3, t, isf);
        P[OG  + t] = ldmix(g,  t, isf);
        P[OBE + t] = ldmix(be, t, isf);
        Xs [(size_t)N * D + t] = 0;     // zero row (index N) for pad edges
        Xs2[(size_t)N * D + t] = 0;
    }
    if (t == 0) P[OPA] = ldmix(pa, 0, isf);
}

// ---- deterministic two-pass radix binning (no global atomics) --------------
// H layout: H[bucket * NBLK + block]

__global__ void binA1_kernel(const int* __restrict__ dst, int E, int NB, int CH,
                             int* __restrict__ H) {
    __shared__ int h[1024];
    int t = threadIdx.x, bb = blockIdx.x;
    for (int i = t; i < NB; i += 256) h[i] = 0;
    __syncthreads();
    int beg = bb * CH, end = beg + CH; if (end > E) end = E;
    for (int e = beg + t; e < end; e += 256)
        atomicAdd(&h[dst[e] >> BK_SHIFT], 1);
    __syncthreads();
    for (int i = t; i < NB; i += 256) H[i * NBLK + bb] = h[i];
}

// per-bucket scan of block-counts; last block also scans totals -> bucket_beg
__global__ void binA2_kernel(int* __restrict__ H, int* __restrict__ T,
                             int* __restrict__ bucket_beg, int* __restrict__ done, int NB) {
    __shared__ int ws[4];
    __shared__ int wx[4];
    int b = blockIdx.x, t = threadIdx.x;
    int lane = t & 63, wid = t >> 6;
    int v = H[b * NBLK + t];
    int incl = v;
#pragma unroll
    for (int off = 1; off < 64; off <<= 1) {
        int u = __shfl_up(incl, off, 64);
        if (lane >= off) incl += u;
    }
    if (lane == 63) ws[wid] = incl;
    __syncthreads();
    if (t == 0) {
        int s = 0;
#pragma unroll
        for (int j = 0; j < 4; ++j) { wx[j] = s; s += ws[j]; }
        atomicExch(&T[b], s);            // device-coherent publish
    }
    __syncthreads();
    H[b * NBLK + t] = wx[wid] + incl - v;
    __threadfence();
    __shared__ int amLast;
    if (t == 0) amLast = (atomicAdd(done, 1) == gridDim.x - 1) ? 1 : 0;
    __syncthreads();
    if (!amLast) return;
    int base = t * 4;
    int v0 = (base + 0 < NB) ? atomicAdd(&T[base + 0], 0) : 0;
    int v1 = (base + 1 < NB) ? atomicAdd(&T[base + 1], 0) : 0;
    int v2 = (base + 2 < NB) ? atomicAdd(&T[base + 2], 0) : 0;
    int v3 = (base + 3 < NB) ? atomicAdd(&T[base + 3], 0) : 0;
    int s4 = v0 + v1 + v2 + v3;
    int incl2 = s4;
#pragma unroll
    for (int off = 1; off < 64; off <<= 1) {
        int u = __shfl_up(incl2, off, 64);
        if (lane >= off) incl2 += u;
    }
    __shared__ int ws2[4];
    if (lane == 63) ws2[wid] = incl2;
    __syncthreads();
    int add = 0;
    for (int j = 0; j < wid; ++j) add += ws2[j];
    int e = add + incl2 - s4;
    if (base + 0 < NB) { bucket_beg[base + 0] = e; e += v0; }
    if (base + 1 < NB) { bucket_beg[base + 1] = e; e += v1; }
    if (base + 2 < NB) { bucket_beg[base + 2] = e; e += v2; }
    if (base + 3 < NB) { bucket_beg[base + 3] = e; e += v3; }
    if (base < NB && NB <= base + 4) bucket_beg[NB] = e;
}

// scatter edges into bucket-grouped tmp via LDS cursors (deterministic ranges)
__global__ void binA4_kernel(const int* __restrict__ src, const int* __restrict__ dst,
                             const int* __restrict__ H, const int* __restrict__ bucket_beg,
                             unsigned int* __restrict__ tmp, int E, int NB, int CH) {
    __shared__ int O[1024];
    int t = threadIdx.x, bb = blockIdx.x;
    for (int i = t; i < NB; i += 256) O[i] = bucket_beg[i] + H[i * NBLK + bb];
    __syncthreads();
    int beg = bb * CH, end = beg + CH; if (end > E) end = E;
    for (int e = beg + t; e < end; e += 256) {
        int d = dst[e];
        int p = atomicAdd(&O[d >> BK_SHIFT], 1);
        tmp[p] = ((unsigned int)src[e] << BK_SHIFT) | (unsigned int)(d & 63);
    }
}

// one block per bucket: per-node count + padded scan (>=32) + L2-local scatter +
// pad-fill with zero-row index N + fused layer-1 prescale
__global__ void binB_kernel(const unsigned int* __restrict__ tmp, const int* __restrict__ bucket_beg,
                            int* __restrict__ row_beg, int* __restrict__ cnt,
                            float* __restrict__ dinv, int* __restrict__ col,
                            const void* __restrict__ X, const int* __restrict__ flag,
                            unsigned short* __restrict__ Xs, int N) {
    __shared__ unsigned int ent[BK_CAP];
    __shared__ int lv[64], lpv[64], lpe[64], lcur[64];
    __shared__ float ldv[64];
    int b = blockIdx.x, t = threadIdx.x;
    int beg = bucket_beg[b], end = bucket_beg[b + 1];
    int colbase = beg + b * PAD_SLACK;
    int m = end - beg;
    bool staged = (m <= BK_CAP);
    if (t < 64) lv[t] = 0;
    __syncthreads();
    for (int i = t; i < m; i += 256) {
        unsigned int e = tmp[beg + i];
        if (staged) ent[i] = e;
        atomicAdd(&lv[e & 63u], 1);
    }
    __syncthreads();
    if (t < 64) {
        int v  = lv[t];
        int pv = (v + 31) & ~31;             // padded to multiple of 32, minimum 32
        if (pv == 0) pv = 32;
        int incl = pv;
#pragma unroll
        for (int off = 1; off < 64; off <<= 1) {
            int u = __shfl_up(incl, off, 64);
            if (t >= off) incl += u;
        }
        int pexcl = incl - pv;
        lpv[t]  = pv;
        lpe[t]  = pexcl;
        lcur[t] = pexcl;
        float dv = rsqrtf((float)(v + 1));
        ldv[t] = dv;
        int node = b * 64 + t;
        if (node < N) {
            row_beg[node] = colbase + pexcl;
            cnt[node]     = pv;              // padded count (loop bound)
            dinv[node]    = dv;
        }
    }
    __syncthreads();
    for (int i = t; i < m; i += 256) {
        unsigned int e = staged ? ent[i] : tmp[beg + i];
        int p = atomicAdd(&lcur[e & 63u], 1);
        col[colbase + p] = (int)(e >> BK_SHIFT);
    }
    // pad fill: positions [v, pv) of each node get the zero-row index N
    for (int i = t; i < 64 * 32; i += 256) {
        int nl = i >> 5, j = i & 31;
        int idx = lv[nl] + j;
        if (idx < lpv[nl]) col[colbase + lpe[nl] + idx] = N;
    }
    // fused layer-1 prescale
    int isf = *flag;
    for (int i = t; i < 64 * 64; i += 256) {
        int nl = i >> 6, f = i & 63;
        int node = b * 64 + nl;
        if (node < N)
            Xs[(size_t)node * D + f] = f2bfbits(ldv[nl] * ldmix(X, (size_t)node * D + f, isf));
    }
}

// ---- feature kernels -------------------------------------------------------

__device__ __forceinline__ void acc8(float* a, v4u v) {
    a[0] += bfbits2f((unsigned short)(v.x & 0xffffu));
    a[1] += bfbits2f((unsigned short)(v.x >> 16));
    a[2] += bfbits2f((unsigned short)(v.y & 0xffffu));
    a[3] += bfbits2f((unsigned short)(v.y >> 16));
    a[4] += bfbits2f((unsigned short)(v.z & 0xffffu));
    a[5] += bfbits2f((unsigned short)(v.z >> 16));
    a[6] += bfbits2f((unsigned short)(v.w & 0xffffu));
    a[7] += bfbits2f((unsigned short)(v.w >> 16));
}

// nontemporal row load: the 6.4MB table has ~0% L1 hit rate (random access) --
// nt skips L1 allocation, freeing L1 miss-tracking for more concurrency.
__device__ __forceinline__ v4u ldrow_nt(const unsigned short* __restrict__ Xs, int s, int sub) {
    return __builtin_nontemporal_load((const v4u*)(Xs + ((size_t)s << 6)) + sub);
}

__device__ __forceinline__ v4u ldrow(const unsigned short* __restrict__ Xs, int s, int sub) {
    return *((const v4u*)(Xs + ((size_t)s << 6)) + sub);
}

// paired static-trip gather (r10 structure, pcnt >= 32 guaranteed by binB):
// one wave aggregates TWO nodes, 8 row loads back-to-back before consuming.
__device__ __forceinline__ void agg_pair(const unsigned short* __restrict__ Xs,
                                         int begA, int pcA, int begB, int pcB,
                                         const int* __restrict__ col,
                                         float dnA, float dnB, int iA, int iB, int lane,
                                         float* __restrict__ xA, float* __restrict__ xB) {
    const int slot = lane >> 3;
    const int sub  = lane & 7;
    v4u svA = ldrow(Xs, iA, sub);                    // self rows (early)
    v4u svB = ldrow(Xs, iB, sub);
    float a[8], b[8];
#pragma unroll
    for (int j = 0; j < 8; ++j) { a[j] = 0.f; b[j] = 0.f; }
    // first chunk of both nodes (always present): 8 row loads in flight
    {
        const int* cA = col + begA;
        const int* cB = col + begB;
        int sA0 = cA[slot], sA1 = cA[8 + slot], sA2 = cA[16 + slot], sA3 = cA[24 + slot];
        int sB0 = cB[slot], sB1 = cB[8 + slot], sB2 = cB[16 + slot], sB3 = cB[24 + slot];
        v4u vA0 = ldrow_nt(Xs, sA0, sub);
        v4u vA1 = ldrow_nt(Xs, sA1, sub);
        v4u vA2 = ldrow_nt(Xs, sA2, sub);
        v4u vA3 = ldrow_nt(Xs, sA3, sub);
        v4u vB0 = ldrow_nt(Xs, sB0, sub);
        v4u vB1 = ldrow_nt(Xs, sB1, sub);
        v4u vB2 = ldrow_nt(Xs, sB2, sub);
        v4u vB3 = ldrow_nt(Xs, sB3, sub);
        acc8(a, vA0); acc8(a, vA1); acc8(a, vA2); acc8(a, vA3);
        acc8(b, vB0); acc8(b, vB1); acc8(b, vB2); acc8(b, vB3);
    }
    // tails (deg > 32)
    for (int c = 32; c < pcA; c += 32) {
        const int* cA = col + begA + c;
        int s0 = cA[slot], s1 = cA[8 + slot], s2 = cA[16 + slot], s3 = cA[24 + slot];
        v4u v0 = ldrow_nt(Xs, s0, sub);
        v4u v1 = ldrow_nt(Xs, s1, sub);
        v4u v2 = ldrow_nt(Xs, s2, sub);
        v4u v3 = ldrow_nt(Xs, s3, sub);
        acc8(a, v0); acc8(a, v1); acc8(a, v2); acc8(a, v3);
    }
    for (int c = 32; c < pcB; c += 32) {
        const int* cB = col + begB + c;
        int s0 = cB[slot], s1 = cB[8 + slot], s2 = cB[16 + slot], s3 = cB[24 + slot];
        v4u v0 = ldrow_nt(Xs, s0, sub);
        v4u v1 = ldrow_nt(Xs, s1, sub);
        v4u v2 = ldrow_nt(Xs, s2, sub);
        v4u v3 = ldrow_nt(Xs, s3, sub);
        acc8(b, v0); acc8(b, v1); acc8(b, v2); acc8(b, v3);
    }
    // reduce the 8 row-slots for both nodes (flip lane bits 3..5)
#pragma unroll
    for (int off = 8; off < 64; off <<= 1) {
#pragma unroll
        for (int j = 0; j < 8; ++j) {
            a[j] += __shfl_xor(a[j], off, 64);
            b[j] += __shfl_xor(b[j], off, 64);
        }
    }
    acc8(a, svA);
    acc8(b, svB);
#pragma unroll
    for (int j = 0; j < 8; ++j) { xA[j] = dnA * a[j]; xB[j] = dnB * b[j]; }
}

// paired wave GEMM: each Wl value read once, used for both nodes (2x FMA ILP)
__device__ __forceinline__ void wave_gemm_pair(const float* __restrict__ Wl,
                                               const float* xA, const float* xB,
                                               int lane, float* oA, float* oB) {
    float a0 = 0.f, a1 = 0.f, b0 = 0.f, b1 = 0.f;
#pragma unroll
    for (int k = 0; k < D; k += 2) {
        float w0 = Wl[(k    ) * D + lane];
        float w1 = Wl[(k + 1) * D + lane];
        float xa0 = __shfl(xA[(k    ) & 7], (k    ) >> 3, 64);
        float xb0 = __shfl(xB[(k    ) & 7], (k    ) >> 3, 64);
        float xa1 = __shfl(xA[(k + 1) & 7], (k + 1) >> 3, 64);
        float xb1 = __shfl(xB[(k + 1) & 7], (k + 1) >> 3, 64);
        a0 = fmaf(xa0, w0, a0);
        b0 = fmaf(xb0, w0, b0);
        a1 = fmaf(xa1, w1, a1);
        b1 = fmaf(xb1, w1, b1);
    }
    *oA = a0 + a1;
    *oB = b0 + b1;
}

__global__ void __launch_bounds__(256)
agg_gemm_kernel(const unsigned short* __restrict__ Xs,
                const int* __restrict__ row_beg, const int* __restrict__ cnt,
                const int* __restrict__ col, const float* __restrict__ dinv,
                const float* __restrict__ W, const float* __restrict__ b,
                const float* __restrict__ pa,
                unsigned short* __restrict__ Xout, int n) {
    __shared__ float Wl[D * D];
    int t = threadIdx.x;
    for (int i = t; i < D * D; i += 256) Wl[i] = W[i];
    __syncthreads();
    int wid = t >> 6, lane = t & 63;
    int nodeA = blockIdx.x * 8 + wid * 2;
    int nodeB = nodeA + 1;
    if (nodeA >= n) return;
    bool vB = (nodeB < n);
    int  iA = nodeA, iB = vB ? nodeB : n;           // n = zero row (safe)
    int  begA = row_beg[nodeA], pcA = cnt[nodeA];
    int  begB = vB ? row_beg[nodeB] : begA, pcB = vB ? cnt[nodeB] : 32;
    float dnA = dinv[nodeA], dnB = vB ? dinv[nodeB] : 0.f;
    float bl = b[lane];
    float pr = pa[0];
    float xA[8], xB[8];
    agg_pair(Xs, begA, pcA, begB, pcB, col, dnA, dnB, iA, iB, lane, xA, xB);
    float accA, accB;
    wave_gemm_pair(Wl, xA, xB, lane, &accA, &accB);
    accA += bl; accB += bl;
    accA = (accA >= 0.f) ? accA : pr * accA;
    accB = (accB >= 0.f) ? accB : pr * accB;
    accA *= dnA; accB *= dnB;                        // prescale for next layer
    Xout[(size_t)nodeA * D + lane] = f2bfbits(accA);
    if (vB) Xout[(size_t)nodeB * D + lane] = f2bfbits(accB);
}

__global__ void __launch_bounds__(256)
agg_gemm_ln_kernel(const unsigned short* __restrict__ Xs,
                   const int* __restrict__ row_beg, const int* __restrict__ cnt,
                   const int* __restrict__ col, const float* __restrict__ dinv,
                   const float* __restrict__ W, const float* __restrict__ b,
                   const float* __restrict__ g, const float* __restrict__ be,
                   const int* __restrict__ flag, void* __restrict__ out, int n) {
    __shared__ float Wl[D * D];
    int t = threadIdx.x;
    for (int i = t; i < D * D; i += 256) Wl[i] = W[i];
    __syncthreads();
    int wid = t >> 6, lane = t & 63;
    int nodeA = blockIdx.x * 8 + wid * 2;
    int nodeB = nodeA + 1;
    if (nodeA >= n) return;
    bool vB = (nodeB < n);
    int  iA = nodeA, iB = vB ? nodeB : n;
    int  begA = row_beg[nodeA], pcA = cnt[nodeA];
    int  begB = vB ? row_beg[nodeB] : begA, pcB = vB ? cnt[nodeB] : 32;
    float dnA = dinv[nodeA], dnB = vB ? dinv[nodeB] : 0.f;
    int   isf = *flag;
    float bl  = b[lane];
    float gl  = g[lane];
    float bel = be[lane];
    float xA[8], xB[8];
    agg_pair(Xs, begA, pcA, begB, pcB, col, dnA, dnB, iA, iB, lane, xA, xB);
    float accA, accB;
    wave_gemm_pair(Wl, xA, xB, lane, &accA, &accB);
    accA += bl; accB += bl;
    float sA = accA, sB = accB;
#pragma unroll
    for (int off = 32; off > 0; off >>= 1) { sA += __shfl_xor(sA, off, 64); sB += __shfl_xor(sB, off, 64); }
    float muA = sA * (1.f / 64.f), muB = sB * (1.f / 64.f);
    float dA = accA - muA, dB = accB - muB;
    float vA2 = dA * dA, vB2 = dB * dB;
#pragma unroll
    for (int off = 32; off > 0; off >>= 1) { vA2 += __shfl_xor(vA2, off, 64); vB2 += __shfl_xor(vB2, off, 64); }
    float rA = rsqrtf(vA2 * (1.f / 64.f) + 1e-5f);
    float rB = rsqrtf(vB2 * (1.f / 64.f) + 1e-5f);
    float oA = dA * rA * gl + bel;
    float oB = dB * rB * gl + bel;
    size_t oiA = (size_t)nodeA * D + lane;
    size_t oiB = (size_t)nodeB * D + lane;
    if (isf) {
        ((float*)out)[oiA] = oA;
        if (vB) ((float*)out)[oiB] = oB;
    } else {
        ((unsigned short*)out)[oiA] = f2bfbits(oA);
        if (vB) ((unsigned short*)out)[oiB] = f2bfbits(oB);
    }
}

// ---- driver ----------------------------------------------------------------

extern "C" void kernel_launch(void* const* d_in, const int* in_sizes, int n_in,
                              void* d_out, int out_size, void* d_ws, size_t ws_size,
                              hipStream_t stream) {
    const void* X   = d_in[0];
    const void* W1  = d_in[1];
    const void* b1  = d_in[2];
    const void* W2  = d_in[3];
    const void* b2  = d_in[4];
    const void* W3  = d_in[5];
    const void* b3  = d_in[6];
    const void* pa  = d_in[7];
    const void* g   = d_in[8];
    const void* be  = d_in[9];
    const int*  ei  = (const int*)d_in[10];

    int N = in_sizes[0] / D;
    int E = in_sizes[10] / 2;
    int NB = (N + 63) >> BK_SHIFT;   // <= 1024 for N <= 65536
    int CH = (E + NBLK - 1) / NBLK;  // edges per radix block
    const int* src = ei;
    const int* dst = ei + E;

    char* p = (char*)d_ws;
    auto alloc = [&](size_t bytes) { void* q = (void*)p; p += (bytes + 255) & ~(size_t)255; return q; };
    int*            flag       = (int*)alloc(4);
    int*            done       = (int*)alloc(4);
    int*            H          = (int*)alloc((size_t)1024 * NBLK * 4);
    int*            T          = (int*)alloc(1024 * 4);
    int*            bucket_beg = (int*)alloc(1025 * 4);
    int*            row_beg    = (int*)alloc((size_t)N * 4);
    int*            cnt        = (int*)alloc((size_t)N * 4);
    float*          dinv       = (float*)alloc((size_t)N * 4);
    int*            col        = (int*)alloc(((size_t)E + (size_t)NB * PAD_SLACK) * 4);
    unsigned int*   tmp        = (unsigned int*)alloc((size_t)E * 4);
    float*          P          = (float*)alloc((size_t)(OPA + 1) * 4);
    unsigned short* Xs         = (unsigned short*)alloc((size_t)(N + 1) * D * 2);
    unsigned short* Xs2        = (unsigned short*)alloc((size_t)(N + 1) * D * 2);
    (void)ws_size; (void)n_in; (void)out_size;

    setup_kernel<<<1, 256, 0, stream>>>(W1, b1, W2, b2, W3, b3, pa, g, be,
                                        flag, done, P, Xs, Xs2, N);

    binA1_kernel<<<NBLK, 256, 0, stream>>>(dst, E, NB, CH, H);
    binA2_kernel<<<NB, 256, 0, stream>>>(H, T, bucket_beg, done, NB);
    binA4_kernel<<<NBLK, 256, 0, stream>>>(src, dst, H, bucket_beg, tmp, E, NB, CH);
    binB_kernel<<<NB, 256, 0, stream>>>(tmp, bucket_beg, row_beg, cnt, dinv, col, X, flag, Xs, N);

    int ngb = (N + 7) / 8;           // 8 nodes per 256-thread block (2 per wave)

    agg_gemm_kernel   <<<ngb, 256, 0, stream>>>(Xs,  row_beg, cnt, col, dinv, P + OW1, P + OB1, P + OPA, Xs2, N);
    agg_gemm_kernel   <<<ngb, 256, 0, stream>>>(Xs2, row_beg, cnt, col, dinv, P + OW2, P + OB2, P + OPA, Xs,  N);
    agg_gemm_ln_kernel<<<ngb, 256, 0, stream>>>(Xs,  row_beg, cnt, col, dinv, P + OW3, P + OB3, P + OG, P + OBE, flag, d_out, N);
}